// Round 10
// baseline (276.494 us; speedup 1.0000x reference)
//
#include <hip/hip_runtime.h>
#include <math.h>

// 10-layer MLP, fp16 MFMA (fp32 acc), two 16-sample tiles in flight/wave.
// R10: weights NOT in LDS. A 1-block prep kernel packs all weight frags
// (f16, fragment-packed, bias as augmented-K column) into d_ws once; the
// main kernel reads them via global_load (L1-hot, 24KB, shared by all
// blocks on a CU). LDS = act tiles only (12.3KB/block) -> 8 blocks/CU,
// 32 waves/CU (VGPR pinned <=64 via launch_bounds(256,8)).
// R9 carried forward: K16/K32 MFMA split, kt1 act region in x16-identity
// layout (linear b64 epilogue), kt0 XOR-swizzled (2-way writes, free),
// all LDS addresses precomputed. Fallback (tiny ws): R9 LDS-weight path.

typedef _Float16 half8 __attribute__((ext_vector_type(8)));
typedef _Float16 half4 __attribute__((ext_vector_type(4)));
typedef _Float16 half2 __attribute__((ext_vector_type(2)));
typedef float f32x4 __attribute__((ext_vector_type(4)));

__device__ __forceinline__ int swz(int a) {  // kt0 byte-offset swizzle
    return a ^ (((a >> 7) & 1) << 4) ^ (((a >> 8) & 1) << 5);
}

__device__ __forceinline__ float swish_f(float a) {
    float e = __expf(-a);
    return a * __builtin_amdgcn_rcpf(1.0f + e);
}

__device__ __forceinline__ half4 pack4(const float (&v)[4]) {
    auto lo = __builtin_amdgcn_cvt_pkrtz(v[0], v[1]);
    auto hi = __builtin_amdgcn_cvt_pkrtz(v[2], v[3]);
    union {
        half4 h4;
        half2 h2[2];
    } u;
    u.h2[0] = __builtin_bit_cast(half2, lo);
    u.h2[1] = __builtin_bit_cast(half2, hi);
    return u.h4;
}

// x32 weight frag (K=32, k=kg*8+e): row=ot*16+lr; k==IN -> bias.
__device__ __forceinline__ half8 make_frag32(const float* __restrict__ W,
                                             const float* __restrict__ b,
                                             int IN, int OUT, int ot, int lr,
                                             int kg) {
    const int r = ot * 16 + lr;
    half8 h;
#pragma unroll
    for (int e = 0; e < 8; ++e) {
        const int k = kg * 8 + e;
        float v = 0.0f;
        if (r < OUT) {
            if (k < IN)
                v = W[r * IN + k];
            else if (k == IN)
                v = b[r];
        }
        h[e] = (_Float16)v;
    }
    return h;
}

// x16 weight frag (K=16, k=kb+kg*4+e): row=ot*16+lr; k==IN -> bias.
__device__ __forceinline__ half4 make_frag16(const float* __restrict__ W,
                                             const float* __restrict__ b,
                                             int IN, int OUT, int ot, int kb,
                                             int lr, int kg) {
    const int r = ot * 16 + lr;
    half4 h;
#pragma unroll
    for (int e = 0; e < 4; ++e) {
        const int k = kb + kg * 4 + e;
        float v = 0.0f;
        if (r < OUT) {
            if (k < IN)
                v = W[r * IN + k];
            else if (k == IN)
                v = b[r];
        }
        h[e] = (_Float16)v;
    }
    return h;
}

// Weight-frag tables (29 frags: 18 x32 + 11 x16).
#define FRAG_TABLES                                                           \
    const float* Wt[10] = {W0, W1, W2, W3, W4, W5, W6, W7, W8, W9};           \
    const float* bt[10] = {b0, b1, b2, b3, b4, b5, b6, b7, b8, b9};           \
    const int INs[10] = {11, 20, 20, 30, 30, 40, 40, 40, 20, 10};             \
    const int OUTs[10] = {20, 20, 30, 30, 40, 40, 40, 20, 10, 1};             \
    const int L32[18] = {1, 1, 2, 2, 3, 3, 4, 4, 4,                           \
                         5, 5, 5, 6, 6, 6, 7, 7, 8};                          \
    const int O32[18] = {0, 1, 0, 1, 0, 1, 0, 1, 2,                           \
                         0, 1, 2, 0, 1, 2, 0, 1, 0};                          \
    const int L16[11] = {0, 0, 5, 5, 5, 6, 6, 6, 7, 7, 9};                    \
    const int O16[11] = {0, 1, 0, 1, 2, 0, 1, 2, 0, 1, 0};                    \
    const int KB16[11] = {0, 0, 32, 32, 32, 32, 32, 32, 32, 32, 0};

#define WPARAMS                                                               \
    const float *__restrict__ W0, const float *__restrict__ b0,               \
        const float *__restrict__ W1, const float *__restrict__ b1,           \
        const float *__restrict__ W2, const float *__restrict__ b2,           \
        const float *__restrict__ W3, const float *__restrict__ b3,           \
        const float *__restrict__ W4, const float *__restrict__ b4,           \
        const float *__restrict__ W5, const float *__restrict__ b5,           \
        const float *__restrict__ W6, const float *__restrict__ b6,           \
        const float *__restrict__ W7, const float *__restrict__ b7,           \
        const float *__restrict__ W8, const float *__restrict__ b8,           \
        const float *__restrict__ W9, const float *__restrict__ b9

// ---- prep kernel: pack 29 weight frags (f16) into d_ws ----
__global__ __launch_bounds__(256) void longnet_prep(WPARAMS,
                                                    _Float16* __restrict__ gw) {
    const int tid = threadIdx.x;
    const int lane = tid & 63;
    const int wave = tid >> 6;
    const int lr = lane & 15;
    const int kg = lane >> 4;
    _Float16* const gw16 = gw + 9216;
    FRAG_TABLES
#pragma unroll
    for (int i = 0; i < 18; ++i)
        if ((i & 3) == wave) {
            const int L = L32[i];
            half8 h = make_frag32(Wt[L], bt[L], INs[L], OUTs[L], O32[i], lr, kg);
            *(half8*)(gw + i * 512 + lane * 8) = h;
        }
#pragma unroll
    for (int i = 0; i < 11; ++i)
        if (((18 + i) & 3) == wave) {
            const int L = L16[i];
            half4 h = make_frag16(Wt[L], bt[L], INs[L], OUTs[L], O16[i],
                                  KB16[i], lr, kg);
            *(half4*)(gw16 + i * 256 + lane * 4) = h;
        }
}

struct TP {                 // per-tile precomputed LDS pointers
    const half8* r0;        // kt0 b128 read (swizzled)
    const half4* r1;        // kt1 b64 read (linear)
    _Float16* w0;           // kt0 write, ot=0 (swizzled)
    _Float16* w1;           // kt0 write, ot=1 (swizzled)
    _Float16* wk;           // kt1 write (linear, == r1 address)
};

template <int NK0, int MARK, int NOT>
__device__ __forceinline__ void epi_kt0(const f32x4 (&A)[NOT], const TP& t,
                                        int kg) {
#pragma unroll
    for (int ot = 0; ot < NK0; ++ot) {
        float v[4];
#pragma unroll
        for (int r = 0; r < 4; ++r) {
            v[r] = swish_f(A[ot][r]);
            if (ot == MARK / 16 && ot * 16 + kg * 4 + r == MARK) v[r] = 1.0f;
        }
        _Float16* wp = (ot == 0) ? t.w0 : t.w1;
        *(half4*)wp = pack4(v);
    }
}

template <int MREL>
__device__ __forceinline__ void epi_kt1(const f32x4& a, const TP& t, int kg) {
    float v[4];
#pragma unroll
    for (int r = 0; r < 4; ++r) {
        v[r] = swish_f(a[r]);
        if constexpr (MREL >= 0) {
            if (kg * 4 + r == MREL) v[r] = 1.0f;
        }
    }
    *(half4*)t.wk = pack4(v);
}

template <int NOT, bool K1>
__device__ __forceinline__ void compute2(const _Float16* __restrict__ w32,
                                         const _Float16* __restrict__ w16,
                                         const TP& t0, const TP& t1,
                                         f32x4 (&A)[NOT], f32x4 (&B)[NOT],
                                         int lane) {
    const f32x4 z4 = {0.f, 0.f, 0.f, 0.f};
    const half8 b0 = *t0.r0;
    const half8 b1 = *t1.r0;
#pragma unroll
    for (int ot = 0; ot < NOT; ++ot) {
        const half8 wf = *(const half8*)(w32 + ot * 512 + lane * 8);
        A[ot] = __builtin_amdgcn_mfma_f32_16x16x32_f16(wf, b0, z4, 0, 0, 0);
        B[ot] = __builtin_amdgcn_mfma_f32_16x16x32_f16(wf, b1, z4, 0, 0, 0);
    }
    if constexpr (K1) {
        const half4 c0 = *t0.r1;
        const half4 c1 = *t1.r1;
#pragma unroll
        for (int ot = 0; ot < NOT; ++ot) {
            const half4 wg = *(const half4*)(w16 + ot * 256 + lane * 4);
            A[ot] = __builtin_amdgcn_mfma_f32_16x16x16f16(wg, c0, A[ot], 0, 0, 0);
            B[ot] = __builtin_amdgcn_mfma_f32_16x16x16f16(wg, c1, B[ot], 0, 0, 0);
        }
    }
}

template <int NOT, bool K1, int NK0, int MARK, int MREL>
__device__ __forceinline__ void layerX(const _Float16* __restrict__ w32,
                                       const _Float16* __restrict__ w16,
                                       const TP& t0, const TP& t1, int lane,
                                       int kg) {
    f32x4 A[NOT], B[NOT];
    compute2<NOT, K1>(w32, w16, t0, t1, A, B, lane);
    epi_kt0<NK0, MARK>(A, t0, kg);
    epi_kt0<NK0, MARK>(B, t1, kg);
    if constexpr (NOT > NK0) {
        epi_kt1<MREL>(A[NK0], t0, kg);
        epi_kt1<MREL>(B[NK0], t1, kg);
    }
}

__device__ __forceinline__ half4 load_x4(const float* __restrict__ x,
                                         int row0, int lr, int kg) {
    half4 b = {};
    const float* xr = x + (size_t)(row0 + lr) * 11;
#pragma unroll
    for (int e = 0; e < 4; ++e) {
        const int k = kg * 4 + e;
        float v = (k < 11) ? xr[k] : ((k == 11) ? 1.0f : 0.0f);
        b[e] = (_Float16)v;
    }
    return b;
}

template <bool GW, int MINW>
__global__ __launch_bounds__(256, MINW) void longnet_mlp_r10(
    const float* __restrict__ x, WPARAMS, const _Float16* __restrict__ gw,
    float* __restrict__ out, int n) {
    // act: 4 waves x 2 tiles x 1536 B = 12288 B (+ s_w only in fallback).
    __shared__ __align__(16) _Float16 s_act[6144];
    __shared__ __align__(16) _Float16 s_w[GW ? 8 : 12032];

    const int tid = threadIdx.x;
    const int lane = tid & 63;
    const int wave = tid >> 6;
    const int lr = lane & 15;
    const int kg = lane >> 4;
    const int kgl = kg & 1;
    const int kgh = kg >> 1;

    const _Float16* wb;  // weight-frag image base (global or LDS)
    if constexpr (GW) {
        wb = gw;
    } else {
        FRAG_TABLES
#pragma unroll
        for (int i = 0; i < 18; ++i)
            if ((i & 3) == wave) {
                const int L = L32[i];
                half8 h = make_frag32(Wt[L], bt[L], INs[L], OUTs[L], O32[i],
                                      lr, kg);
                *(half8*)(s_w + i * 512 + lane * 8) = h;
            }
#pragma unroll
        for (int i = 0; i < 11; ++i)
            if (((18 + i) & 3) == wave) {
                const int L = L16[i];
                half4 h = make_frag16(Wt[L], bt[L], INs[L], OUTs[L], O16[i],
                                      KB16[i], lr, kg);
                *(half4*)(s_w + 9216 + i * 256 + lane * 4) = h;
            }
        wb = s_w;
    }
    const _Float16* const w16 = wb + 9216;

    // ---- per-tile pointer setup (all LDS addresses precomputed) ----
    char* const c0 = (char*)s_act + wave * 3072;
    char* const c1 = c0 + 1536;
    const int rd0 = swz(lane * 16);
    const int rk1 = 1024 + lane * 8;
    const int wo0 = swz((kgh & 3) * 256 + lr * 16 + kgl * 8);
    const int wo1 = swz(((2 + kgh) & 3) * 256 + lr * 16 + kgl * 8);
    const TP t0 = {(const half8*)(c0 + rd0), (const half4*)(c0 + rk1),
                   (_Float16*)(c0 + wo0), (_Float16*)(c0 + wo1),
                   (_Float16*)(c0 + rk1)};
    const TP t1 = {(const half8*)(c1 + rd0), (const half4*)(c1 + rk1),
                   (_Float16*)(c1 + wo0), (_Float16*)(c1 + wo1),
                   (_Float16*)(c1 + rk1)};

    // zero both act tiles once (3072 B = 768 dwords), wave-owned.
    {
        int* a32 = (int*)c0;
#pragma unroll
        for (int i = 0; i < 12; ++i) a32[i * 64 + lane] = 0;
    }
    if constexpr (!GW) __syncthreads();

    const f32x4 z4 = {0.f, 0.f, 0.f, 0.f};
    const int npair = n >> 5;  // 62500 pair-tiles of 32 rows
    const int step = (int)gridDim.x * 4;

    for (int t = blockIdx.x * 4 + wave; t < npair; t += step) {
        const int row0 = t * 32;

        // L0 (11->20): single x16 MFMA, B straight from global x.
        {
            const half4 xb0 = load_x4(x, row0, lr, kg);
            const half4 xb1 = load_x4(x, row0 + 16, lr, kg);
            f32x4 A[2], B[2];
#pragma unroll
            for (int ot = 0; ot < 2; ++ot) {
                const half4 wg = *(const half4*)(w16 + ot * 256 + lane * 4);
                A[ot] = __builtin_amdgcn_mfma_f32_16x16x16f16(wg, xb0, z4, 0, 0, 0);
                B[ot] = __builtin_amdgcn_mfma_f32_16x16x16f16(wg, xb1, z4, 0, 0, 0);
            }
            epi_kt0<2, 20>(A, t0, kg);
            epi_kt0<2, 20>(B, t1, kg);
        }
        layerX<2, false, 2, 20, -1>(wb + 0 * 512, w16, t0, t1, lane, kg);   // L1
        layerX<2, false, 2, 30, -1>(wb + 2 * 512, w16, t0, t1, lane, kg);   // L2
        layerX<2, false, 2, 30, -1>(wb + 4 * 512, w16, t0, t1, lane, kg);   // L3
        layerX<3, false, 2, 1000, 8>(wb + 6 * 512, w16, t0, t1, lane, kg);  // L4
        layerX<3, true, 2, 1000, 8>(wb + 9 * 512, w16 + 2 * 256, t0, t1, lane, kg);   // L5
        layerX<3, true, 2, 1000, 8>(wb + 12 * 512, w16 + 5 * 256, t0, t1, lane, kg);  // L6
        layerX<2, true, 2, 20, -1>(wb + 15 * 512, w16 + 8 * 256, t0, t1, lane, kg);   // L7
        layerX<1, false, 0, 1000, 10>(wb + 17 * 512, w16, t0, t1, lane, kg);          // L8 -> kt1

        // L9 (10->1) + ReLU: single x16 on kt1; feature 0 at kg==0, r==0.
        {
            const half4 wg = *(const half4*)(w16 + 10 * 256 + lane * 4);
            f32x4 F0 = __builtin_amdgcn_mfma_f32_16x16x16f16(wg, *t0.r1, z4, 0, 0, 0);
            f32x4 F1 = __builtin_amdgcn_mfma_f32_16x16x16f16(wg, *t1.r1, z4, 0, 0, 0);
            if (kg == 0) {
                out[row0 + lr] = fmaxf(F0[0], 0.0f);
                out[row0 + 16 + lr] = fmaxf(F1[0], 0.0f);
            }
        }
    }
}

extern "C" void kernel_launch(void* const* d_in, const int* in_sizes, int n_in,
                              void* d_out, int out_size, void* d_ws, size_t ws_size,
                              hipStream_t stream) {
    const float* x = (const float*)d_in[0];
    const float* W0 = (const float*)d_in[1];
    const float* b0 = (const float*)d_in[2];
    const float* W1 = (const float*)d_in[3];
    const float* b1 = (const float*)d_in[4];
    const float* W2 = (const float*)d_in[5];
    const float* b2 = (const float*)d_in[6];
    const float* W3 = (const float*)d_in[7];
    const float* b3 = (const float*)d_in[8];
    const float* W4 = (const float*)d_in[9];
    const float* b4 = (const float*)d_in[10];
    const float* W5 = (const float*)d_in[11];
    const float* b5 = (const float*)d_in[12];
    const float* W6 = (const float*)d_in[13];
    const float* b6 = (const float*)d_in[14];
    const float* W7 = (const float*)d_in[15];
    const float* b7 = (const float*)d_in[16];
    const float* W8 = (const float*)d_in[17];
    const float* b8 = (const float*)d_in[18];
    const float* W9 = (const float*)d_in[19];
    const float* b9 = (const float*)d_in[20];
    float* out = (float*)d_out;

    const int n = in_sizes[0] / 11;  // 2,000,000 rows
    const size_t WBYTES = 12032 * sizeof(_Float16);  // 24064 B frag image

    if (ws_size >= WBYTES) {
        _Float16* gw = (_Float16*)d_ws;
        longnet_prep<<<1, 256, 0, stream>>>(
            W0, b0, W1, b1, W2, b2, W3, b3, W4, b4, W5, b5, W6, b6, W7, b7,
            W8, b8, W9, b9, gw);
        longnet_mlp_r10<true, 8><<<2048, 256, 0, stream>>>(
            x, W0, b0, W1, b1, W2, b2, W3, b3, W4, b4, W5, b5, W6, b6, W7, b7,
            W8, b8, W9, b9, gw, out, n);
    } else {
        longnet_mlp_r10<false, 4><<<1024, 256, 0, stream>>>(
            x, W0, b0, W1, b1, W2, b2, W3, b3, W4, b4, W5, b5, W6, b6, W7, b7,
            W8, b8, W9, b9, nullptr, out, n);
    }
}

// Round 11
// 182.039 us; speedup vs baseline: 1.5189x; 1.5189x over previous
//
#include <hip/hip_runtime.h>
#include <math.h>

// 10-layer MLP, ALL-K16 MFMA (16x16x16f16), activations REGISTER-RESIDENT.
// R11 insight (HW-validated by R9's kt1 path + L0/L9): for 16x16x16f16 the
// D-layout (f=kg*4+r, sample=lane&15) == B-frag layout (k=kg*4+e). So each
// layer's acc group ot IS the next layer's B-frag for k-block ot: the whole
// MLP chains in registers; LDS holds only 47 x16 weight frags (24 KB,
// linear b64 reads). No act LDS -> 4 tiles (64 rows) in flight per wave for
// ILP at zero LDS cost. Bias via augmented-K (marker 1.0 at feature==OUT).
// R6/R10 lesson: launch_bounds(256,4) only; never force 8 waves/EU (the
// 64-reg unified budget spills catastrophically).

typedef _Float16 half4 __attribute__((ext_vector_type(4)));
typedef _Float16 half2 __attribute__((ext_vector_type(2)));
typedef float f32x4 __attribute__((ext_vector_type(4)));

#define T 4  // 16-row tiles in flight per wave

__device__ __forceinline__ float swish_f(float a) {
    float e = __expf(-a);
    return a * __builtin_amdgcn_rcpf(1.0f + e);
}

__device__ __forceinline__ half4 pack4(const float (&v)[4]) {
    auto lo = __builtin_amdgcn_cvt_pkrtz(v[0], v[1]);
    auto hi = __builtin_amdgcn_cvt_pkrtz(v[2], v[3]);
    union {
        half4 h4;
        half2 h2[2];
    } u;
    u.h2[0] = __builtin_bit_cast(half2, lo);
    u.h2[1] = __builtin_bit_cast(half2, hi);
    return u.h4;
}

// x16 weight frag (K=16, k=kb+kg*4+e): row=ot*16+lr; k==IN -> bias.
__device__ __forceinline__ half4 make_frag16(const float* __restrict__ W,
                                             const float* __restrict__ b,
                                             int IN, int OUT, int ot, int kb,
                                             int lr, int kg) {
    const int r = ot * 16 + lr;
    half4 h;
#pragma unroll
    for (int e = 0; e < 4; ++e) {
        const int k = kb + kg * 4 + e;
        float v = 0.0f;
        if (r < OUT) {
            if (k < IN)
                v = W[r * IN + k];
            else if (k == IN)
                v = b[r];
        }
        h[e] = (_Float16)v;
    }
    return h;
}

// One layer for all T tiles, register-chained.
// bf[t][0..NKT-1] in (x16 B-frag layout) -> bf[t][0..NOT-1] out.
// MARK = OUT = next layer's bias column.
template <int NKT, int NOT, int MARK>
__device__ __forceinline__ void layerR(const _Float16* __restrict__ wb,
                                       half4 (&bf)[T][3], int lane, int kg) {
    const f32x4 z4 = {0.f, 0.f, 0.f, 0.f};
    f32x4 acc[T][NOT];
#pragma unroll
    for (int kt = 0; kt < NKT; ++kt) {
#pragma unroll
        for (int ot = 0; ot < NOT; ++ot) {
            const half4 wg =
                *(const half4*)(wb + (ot * NKT + kt) * 256 + lane * 4);
#pragma unroll
            for (int t = 0; t < T; ++t)
                acc[t][ot] = __builtin_amdgcn_mfma_f32_16x16x16f16(
                    wg, bf[t][kt], kt == 0 ? z4 : acc[t][ot], 0, 0, 0);
        }
    }
#pragma unroll
    for (int t = 0; t < T; ++t) {
#pragma unroll
        for (int ot = 0; ot < NOT; ++ot) {
            float v[4];
#pragma unroll
            for (int r = 0; r < 4; ++r) {
                v[r] = swish_f(acc[t][ot][r]);
                if (ot == MARK / 16 && ot * 16 + kg * 4 + r == MARK)
                    v[r] = 1.0f;
            }
            bf[t][ot] = pack4(v);
        }
    }
}

__device__ __forceinline__ half4 load_x4(const float* __restrict__ x,
                                         int row0, int lr, int kg) {
    half4 b = {};
    const float* xr = x + (size_t)(row0 + lr) * 11;
#pragma unroll
    for (int e = 0; e < 4; ++e) {
        const int k = kg * 4 + e;
        float v = (k < 11) ? xr[k] : ((k == 11) ? 1.0f : 0.0f);
        b[e] = (_Float16)v;
    }
    return b;
}

__global__ __launch_bounds__(256, 4) void longnet_mlp_r11(
    const float* __restrict__ x,
    const float* __restrict__ W0, const float* __restrict__ b0,
    const float* __restrict__ W1, const float* __restrict__ b1,
    const float* __restrict__ W2, const float* __restrict__ b2,
    const float* __restrict__ W3, const float* __restrict__ b3,
    const float* __restrict__ W4, const float* __restrict__ b4,
    const float* __restrict__ W5, const float* __restrict__ b5,
    const float* __restrict__ W6, const float* __restrict__ b6,
    const float* __restrict__ W7, const float* __restrict__ b7,
    const float* __restrict__ W8, const float* __restrict__ b8,
    const float* __restrict__ W9, const float* __restrict__ b9,
    float* __restrict__ out, int n) {
    // LDS: 47 x16 weight frags x 512 B = 24064 B. No activation LDS.
    __shared__ __align__(16) _Float16 s_w[47 * 256];

    const int tid = threadIdx.x;
    const int lane = tid & 63;
    const int wave = tid >> 6;
    const int lr = lane & 15;
    const int kg = lane >> 4;

    // ---- stage 47 weight frags (4 waves round-robin) ----
    {
        const float* Wt[10] = {W0, W1, W2, W3, W4, W5, W6, W7, W8, W9};
        const float* bt[10] = {b0, b1, b2, b3, b4, b5, b6, b7, b8, b9};
        const int INs[10] = {11, 20, 20, 30, 30, 40, 40, 40, 20, 10};
        const int OUTs[10] = {20, 20, 30, 30, 40, 40, 40, 20, 10, 1};
        const int NOTs[10] = {2, 2, 2, 2, 3, 3, 3, 2, 1, 1};
        const int NKTs[10] = {1, 2, 2, 2, 2, 3, 3, 3, 2, 1};
        int f = 0;
        for (int L = 0; L < 10; ++L)
            for (int ot = 0; ot < NOTs[L]; ++ot)
                for (int kt = 0; kt < NKTs[L]; ++kt, ++f)
                    if ((f & 3) == wave) {
                        half4 h = make_frag16(Wt[L], bt[L], INs[L], OUTs[L],
                                              ot, kt * 16, lr, kg);
                        *(half4*)(s_w + f * 256 + lane * 4) = h;
                    }
    }
    __syncthreads();

    const f32x4 z4 = {0.f, 0.f, 0.f, 0.f};
    const int ngrp = n >> 6;  // 64-row groups; n = 2e6 -> 31250 exact
    const int step = (int)gridDim.x * 4;

    for (int g = blockIdx.x * 4 + wave; g < ngrp; g += step) {
        const int row0 = g * 64;

        half4 bf[T][3];
#pragma unroll
        for (int t = 0; t < T; ++t)
            bf[t][0] = load_x4(x, row0 + t * 16, lr, kg);

        layerR<1, 2, 20>(s_w + 0 * 256, bf, lane, kg);   // L0 11->20
        layerR<2, 2, 20>(s_w + 2 * 256, bf, lane, kg);   // L1 20->20
        layerR<2, 2, 30>(s_w + 6 * 256, bf, lane, kg);   // L2 20->30
        layerR<2, 2, 30>(s_w + 10 * 256, bf, lane, kg);  // L3 30->30
        layerR<2, 3, 40>(s_w + 14 * 256, bf, lane, kg);  // L4 30->40
        layerR<3, 3, 40>(s_w + 20 * 256, bf, lane, kg);  // L5 40->40
        layerR<3, 3, 40>(s_w + 29 * 256, bf, lane, kg);  // L6 40->40
        layerR<3, 2, 20>(s_w + 38 * 256, bf, lane, kg);  // L7 40->20
        layerR<2, 1, 10>(s_w + 44 * 256, bf, lane, kg);  // L8 20->10

        // L9 (10->1) + ReLU: feature 0 at kg==0, reg 0; sample = lr.
        {
            const half4 wg = *(const half4*)(s_w + 46 * 256 + lane * 4);
#pragma unroll
            for (int t = 0; t < T; ++t) {
                f32x4 F = __builtin_amdgcn_mfma_f32_16x16x16f16(
                    wg, bf[t][0], z4, 0, 0, 0);
                if (kg == 0) out[row0 + t * 16 + lr] = fmaxf(F[0], 0.0f);
            }
        }
    }
}

extern "C" void kernel_launch(void* const* d_in, const int* in_sizes, int n_in,
                              void* d_out, int out_size, void* d_ws, size_t ws_size,
                              hipStream_t stream) {
    const float* x = (const float*)d_in[0];
    const float* W0 = (const float*)d_in[1];
    const float* b0 = (const float*)d_in[2];
    const float* W1 = (const float*)d_in[3];
    const float* b1 = (const float*)d_in[4];
    const float* W2 = (const float*)d_in[5];
    const float* b2 = (const float*)d_in[6];
    const float* W3 = (const float*)d_in[7];
    const float* b3 = (const float*)d_in[8];
    const float* W4 = (const float*)d_in[9];
    const float* b4 = (const float*)d_in[10];
    const float* W5 = (const float*)d_in[11];
    const float* b5 = (const float*)d_in[12];
    const float* W6 = (const float*)d_in[13];
    const float* b6 = (const float*)d_in[14];
    const float* W7 = (const float*)d_in[15];
    const float* b7 = (const float*)d_in[16];
    const float* W8 = (const float*)d_in[17];
    const float* b8 = (const float*)d_in[18];
    const float* W9 = (const float*)d_in[19];
    const float* b9 = (const float*)d_in[20];
    float* out = (float*)d_out;

    const int n = in_sizes[0] / 11;  // 2,000,000 rows (divisible by 64)
    const int grid = 1024;           // persistent; 4 blocks/CU

    longnet_mlp_r11<<<grid, 256, 0, stream>>>(
        x, W0, b0, W1, b1, W2, b2, W3, b3, W4, b4, W5, b5, W6, b6, W7, b7, W8,
        b8, W9, b9, out, n);
}